// Round 14
// baseline (120.608 us; speedup 1.0000x reference)
//
#include <hip/hip_runtime.h>
#include <math.h>

#define N_PATHS 23
#define HIDDEN  32
#define N_NODES 4096
#define N_EDGES 8192
#define FEAT    512
#define BLK     128   // 2 waves; 4 edges per wave (R11/R20/R22 structure; R25 split accumulators)
#define ZERO_BLOCKS 256

// R22: COMPILER-ONLY phase separator (see R22 notes: per-wave DS ops are in-order;
// compiler inserts counted lgkmcnt for true data deps; clobber pins placement).
#define WAVE_SYNC() asm volatile("" ::: "memory")

typedef __attribute__((ext_vector_type(8)))  short bf16x8;
typedef __attribute__((ext_vector_type(16))) float f32x16;

// ---- compile-time path metadata (PATHS enumeration: l1 outer, l2, l3) ----
constexpr int cL1[N_PATHS] = {0,0,0,0, 1,1,1,1,1,1, 2,2,2,2,2,2,2, 3,3,3,3,3,3};
constexpr int cL2[N_PATHS] = {0,1,2,3, 0,1,1,2,2,3, 0,1,1,2,2,3,3, 0,1,2,2,3,3};
constexpr int cCOFF[N_PATHS]= {0,1,10,35,84,93,102,147,192,297,402,427,472,577,602,727,832,1077,1126,1231,1336,1581,1630};
constexpr int cL3P[N_PATHS] = {0,5,13,21, 1,4,7,11,15,19, 2,6,9,10,14,18,22, 3,8,12,16,17,20};
constexpr int cL3S[5] = {0,4,10,17,23};
constexpr int cOFF3[4] = {0,32,128,288};
__device__ const int CNT_L3[4] = {4,6,7,6};
__device__ const int D_L3[N_PATHS] = {0,1,2,3, 1,0,2,1,3,2, 2,1,3,0,2,1,3, 3,2,1,3,0,2};

// per-edge z offset of path slot pi within its group's batched z buffer
constexpr int zOff(int G, int pi) {
    int off = 0;
    for (int q = cL3S[G]; q < pi; ++q) off += (2*cL1[cL3P[q]]+1)*(2*G+1);
    return off;
}
// max per-edge z total over groups: G3 = 196 -> 4*196 = 784 floats

constexpr int grpN (int G)        { return cL3S[G+1] - cL3S[G]; }
constexpr int pSlot(int G, int i) { return cL3P[cL3S[G] + i]; }
constexpr int zO   (int G, int i) { return zOff(G, cL3S[G] + i); }
// A-pointer offset and z float offset for slot i of group G (wave-uniform scalars)
constexpr int pOffA(int G, int i) { return pSlot(G,i) * 1024; }
constexpr int zOff4(int G, int i) { return 4 * zO(G,i); }

// ---- 8-point Gauss-Legendre nodes/weights (128-pt rule: exact for degree<=9 SH triple products) ----
__device__ const double GLX8[8] = {
    -0.96028985649753623168, -0.79666647741362673959, -0.52553240991632898582, -0.18343464249564980494,
     0.18343464249564980494,  0.52553240991632898582,  0.79666647741362673959,  0.96028985649753623168};
__device__ const double GLW8[8] = {
     0.10122853629037625915,  0.22238103445337447054,  0.31370664587788728734,  0.36268378337836198297,
     0.36268378337836198297,  0.31370664587788728734,  0.22238103445337447054,  0.10122853629037625915};
// cos/sin(k*pi/8), k=0..15 — exact literals
__device__ const double COSP16[16] = {
  1.0,                     0.92387953251128675613,  0.70710678118654752440,  0.38268343236508977173,
  0.0,                    -0.38268343236508977173, -0.70710678118654752440, -0.92387953251128675613,
 -1.0,                    -0.92387953251128675613, -0.70710678118654752440, -0.38268343236508977173,
  0.0,                     0.38268343236508977173,  0.70710678118654752440,  0.92387953251128675613};
__device__ const double SINP16[16] = {
  0.0,                     0.38268343236508977173,  0.70710678118654752440,  0.92387953251128675613,
  1.0,                     0.92387953251128675613,  0.70710678118654752440,  0.38268343236508977173,
  0.0,                    -0.38268343236508977173, -0.70710678118654752440, -0.92387953251128675613,
 -1.0,                    -0.92387953251128675613, -0.70710678118654752440, -0.38268343236508977173};

__device__ inline void sh_f64(double x, double y, double z, double* Y) {
    const double s3 = 1.7320508075688772935, s5 = 2.2360679774997896964,
                 s7 = 2.6457513110645905905, s15 = 3.8729833462074168852;
    const double c58 = 0.79056941504209483300, c38 = 0.61237243569579452455;
    Y[0] = 1.0;
    Y[1] = s3*x;  Y[2] = s3*y;  Y[3] = s3*z;
    Y[4] = s5*s3*x*z;  Y[5] = s5*s3*x*y;
    Y[6] = s5*(y*y - 0.5*(x*x + z*z));
    Y[7] = s5*s3*y*z;  Y[8] = s5*(s3/2.0)*(z*z - x*x);
    Y[9] = s7*c58*x*(3.0*z*z - x*x);
    Y[10]= s7*s15*x*y*z;
    Y[11]= s7*c38*x*(5.0*y*y - 1.0);
    Y[12]= s7*0.5*y*(5.0*y*y - 3.0);
    Y[13]= s7*c38*z*(5.0*y*y - 1.0);
    Y[14]= s7*(s15/2.0)*y*(z*z - x*x);
    Y[15]= s7*c58*z*(z*z - 3.0*x*x);
}

__device__ inline void sh_f32(float x, float y, float z, float* Y) {
    const float s3 = 1.73205080757f, s5 = 2.23606797750f, s7 = 2.64575131106f, s15 = 3.87298334621f;
    const float c58 = 0.79056941504f, c38 = 0.61237243570f;
    Y[0] = 1.0f;
    Y[1] = s3*x;  Y[2] = s3*y;  Y[3] = s3*z;
    Y[4] = s15*x*z;  Y[5] = s15*x*y;
    Y[6] = s5*(y*y - 0.5f*(x*x + z*z));
    Y[7] = s15*y*z;  Y[8] = s5*(s3*0.5f)*(z*z - x*x);
    Y[9] = s7*c58*x*(3.0f*z*z - x*x);
    Y[10]= s7*s15*x*y*z;
    Y[11]= s7*c38*x*(5.0f*y*y - 1.0f);
    Y[12]= s7*0.5f*y*(5.0f*y*y - 3.0f);
    Y[13]= s7*c38*z*(5.0f*y*y - 1.0f);
    Y[14]= s7*(s15*0.5f)*y*(z*z - x*x);
    Y[15]= s7*c58*z*(z*z - 3.0f*x*x);
}

__device__ inline unsigned short bf16rne(float x) {
    unsigned int u = __float_as_uint(x);
    unsigned int r = (u + 0x7FFFu + ((u >> 16) & 1u)) >> 16;
    return (unsigned short)r;
}
__device__ inline float bf16f(unsigned short h) {
    return __uint_as_float(((unsigned int)h) << 16);
}

// ---- setup: W3J tables (128-pt quadrature) + weight transpose + output zeroing ----
__global__ __launch_bounds__(512) void w3j_setup_kernel(
    const float* __restrict__ ww, const float* __restrict__ wb,
    float* __restrict__ g_w3j,
    unsigned short* __restrict__ Awhi, unsigned short* __restrict__ Awlo,
    unsigned short* __restrict__ Abhi, unsigned short* __restrict__ Ablo,
    float* __restrict__ out) {
    const int t = threadIdx.x;

    if (blockIdx.x >= N_PATHS) {   // zero-blocks
        const int b = blockIdx.x - N_PATHS;
        float4* o4 = (float4*)(out + (size_t)b * (N_NODES*FEAT/ZERO_BLOCKS));
#pragma unroll
        for (int r = 0; r < 4; ++r)
            o4[t + 512*r] = make_float4(0.f,0.f,0.f,0.f);
        return;
    }

    __shared__ float s_Yq[128][17];
    __shared__ float s_wq[128];
    __shared__ float s_part[256];
    __shared__ float red[256];
    __shared__ float s_scale;

    const int p = blockIdx.x;
    const int l1 = cL1[p], l2 = cL2[p];
    const int l3 = D_L3[p];
    const int d2 = 2*l2+1, d3 = 2*l3+1;
    const int csize = (2*l1+1)*d2*d3;
    const double step = 2.0*3.14159265358979323846/16.0;

    // weight transpose to A-layout [p][w][u], bf16 hi/lo split
#pragma unroll
    for (int r = 0; r < 2; ++r) {
        const int idx = t + 512*r;
        const int w = idx >> 5, u = idx & 31;
        const float vw = ww[p*1024 + u*32 + w];
        const float vb = wb[p*1024 + u*32 + w];
        const unsigned short hw = bf16rne(vw);
        const unsigned short hb = bf16rne(vb);
        const int o = p*1024 + w*32 + u;
        Awhi[o] = hw;  Awlo[o] = bf16rne(vw - bf16f(hw));
        Abhi[o] = hb;  Ablo[o] = bf16rne(vb - bf16f(hb));
    }

    // phase A: one quadrature point per thread (first 128 threads)
    if (t < 128) {
        const int iu = t >> 4, ip = t & 15;
        const double u = GLX8[iu];
        const double st = sqrt(fmax(1.0 - u*u, 0.0));
        double Y[16];
        sh_f64(st*COSP16[ip], st*SINP16[ip], u, Y);
#pragma unroll
        for (int i = 0; i < 16; ++i) s_Yq[t][i] = (float)Y[i];
        s_wq[t] = (float)(GLW8[iu] * step);
    }
    __syncthreads();

    // phase B: 4 threads/entry, 32 interleaved points each, shuffle-reduce
    const int entry0 = t >> 2, sub = t & 3;
#pragma unroll
    for (int pass = 0; pass < 2; ++pass) {
        const int entry = entry0 + pass*128;
        float acc = 0.f;
        if (entry < csize) {
            const int i = entry/(d2*d3); const int r = entry - i*(d2*d3);
            const int j = r/d3; const int k = r - j*d3;
            const int ai = l1*l1+i, bi = l2*l2+j, ci = l3*l3+k;
#pragma unroll 4
            for (int it = 0; it < 32; ++it) {
                const int q = it*4 + sub;
                acc = fmaf(s_wq[q] * s_Yq[q][ai] * s_Yq[q][bi], s_Yq[q][ci], acc);
            }
        }
        acc += __shfl_xor(acc, 1);
        acc += __shfl_xor(acc, 2);
        if (sub == 0 && entry < csize) s_part[entry] = acc;
    }
    __syncthreads();

    if (t < 256) { const float v = (t < csize) ? s_part[t] : 0.f; red[t] = v*v; }
    __syncthreads();
    for (int s = 128; s > 0; s >>= 1) {
        if (t < s) red[t] += red[t+s];
        __syncthreads();
    }
    if (t == 0) {
        const float pw = sqrtf((float)(2*l3+1) / ((float)CNT_L3[l3] * (float)HIDDEN));
        s_scale = pw / sqrtf(red[0]);
    }
    __syncthreads();
    if (t < csize) g_w3j[cCOFF[p] + t] = s_part[t] * s_scale;
}

// ---- batched z for one path (no sync): z[el][i][k] into group z buffer ----
template<int G, int P, int ZOFF>
__device__ __forceinline__ void do_zpath(
    int lane, const float* __restrict__ w3j, const float* sY, float* sz)
{
    constexpr int l1 = cL1[P], l2 = cL2[P];
    constexpr int d1 = 2*l1+1, d2 = 2*l2+1, d3 = 2*G+1;
    constexpr int zc = d1*d3;
#pragma unroll
    for (int base = 0; base < 4*zc; base += 64) {
        const int idx = base + lane;
        if (idx < 4*zc) {
            const int elz = idx / zc;          // const-div
            const int r = idx - elz*zc;
            const int i = r / d3, k = r - i*d3;
            const float* Cp = w3j + cCOFF[P] + i*(d2*d3) + k;
            const float* Yp = sY + elz*16 + l2*l2;
            float acc = 0.f;
#pragma unroll
            for (int j = 0; j < d2; ++j) acc = fmaf(Yp[j], Cp[j*d3], acc);
            sz[4*ZOFF + elz*zc + r] = acc;
        }
    }
}

// ---- ONE path body (R25: kc-split accumulators halve the MFMA dep chain) ----
template<int G, int D1>
__device__ __forceinline__ void path_body(
    int Poff, int zoff4,                       // wave-uniform: A table offset, z float offset
    int el4, int u0, int bvaddr, int avaddr,
    const float (&xr0)[16], const float (&xr1)[16],
    const unsigned short* __restrict__ Awhi, const unsigned short* __restrict__ Awlo,
    const unsigned short* __restrict__ Abhi, const unsigned short* __restrict__ Ablo,
    const float* sz,
    unsigned short* sbh, unsigned short* sbl,
    f32x16 &Cw0, f32x16 &Cb0, f32x16 &Cw1, f32x16 &Cb1)
{
    constexpr int d3 = 2*G+1;
    constexpr int zc = D1*d3;
    constexpr int l1 = (D1-1)/2;
    constexpr int xo = l1*l1;

    // A-operand loads (global/L2) BEFORE the tmp VALU block hides their latency
    bf16x8 awh[2], awl[2], abh[2], abl[2];
#pragma unroll
    for (int kc = 0; kc < 2; ++kc) {
        awh[kc] = *(const bf16x8*)(Awhi + Poff + avaddr + kc*16);
        awl[kc] = *(const bf16x8*)(Awlo + Poff + avaddr + kc*16);
        abh[kc] = *(const bf16x8*)(Abhi + Poff + avaddr + kc*16);
        abl[kc] = *(const bf16x8*)(Ablo + Poff + avaddr + kc*16);
    }

    // tmp[u][k] = sum_i x[u,i]*z[i,k] for u=2u0,2u0+1; chop-split bf16; packed u32 stores
    {
        const float* zr = sz + zoff4 + el4*zc;
        unsigned short* bh = sbh + (el4*d3)*40 + 2*u0;
        unsigned short* bl = sbl + (el4*d3)*40 + 2*u0;
#pragma unroll
        for (int k = 0; k < d3; ++k) {
            float t0 = 0.f, t1 = 0.f;
#pragma unroll
            for (int i = 0; i < D1; ++i) {
                const float zz = zr[i*d3 + k];
                t0 = fmaf(xr0[xo+i], zz, t0);
                t1 = fmaf(xr1[xo+i], zz, t1);
            }
            const unsigned int b0 = __float_as_uint(t0);
            const unsigned int b1 = __float_as_uint(t1);
            const float l0 = t0 - __uint_as_float(b0 & 0xFFFF0000u);
            const float l1f = t1 - __uint_as_float(b1 & 0xFFFF0000u);
            *(unsigned int*)(bh + k*40) = (b0 >> 16) | (b1 & 0xFFFF0000u);
            *(unsigned int*)(bl + k*40) = (__float_as_uint(l0) >> 16) | (__float_as_uint(l1f) & 0xFFFF0000u);
        }
    }
    WAVE_SYNC();   // placement fence only: stores stay before reads (in-order DS does the rest)

    // B loads + 12 MFMA: kc=0 -> {Cw0,Cb0}, kc=1 -> {Cw1,Cb1} (4 independent chains)
    __builtin_amdgcn_s_setprio(1);
    {
        const bf16x8 bh0 = *(const bf16x8*)(sbh + bvaddr);
        const bf16x8 bl0 = *(const bf16x8*)(sbl + bvaddr);
        const bf16x8 bh1 = *(const bf16x8*)(sbh + bvaddr + 16);
        const bf16x8 bl1 = *(const bf16x8*)(sbl + bvaddr + 16);
        Cw0 = __builtin_amdgcn_mfma_f32_32x32x16_bf16(awh[0], bh0, Cw0, 0, 0, 0);
        Cb0 = __builtin_amdgcn_mfma_f32_32x32x16_bf16(abh[0], bh0, Cb0, 0, 0, 0);
        Cw1 = __builtin_amdgcn_mfma_f32_32x32x16_bf16(awh[1], bh1, Cw1, 0, 0, 0);
        Cb1 = __builtin_amdgcn_mfma_f32_32x32x16_bf16(abh[1], bh1, Cb1, 0, 0, 0);
        Cw0 = __builtin_amdgcn_mfma_f32_32x32x16_bf16(awh[0], bl0, Cw0, 0, 0, 0);
        Cb0 = __builtin_amdgcn_mfma_f32_32x32x16_bf16(abh[0], bl0, Cb0, 0, 0, 0);
        Cw1 = __builtin_amdgcn_mfma_f32_32x32x16_bf16(awh[1], bl1, Cw1, 0, 0, 0);
        Cb1 = __builtin_amdgcn_mfma_f32_32x32x16_bf16(abh[1], bl1, Cb1, 0, 0, 0);
        Cw0 = __builtin_amdgcn_mfma_f32_32x32x16_bf16(awl[0], bh0, Cw0, 0, 0, 0);
        Cb0 = __builtin_amdgcn_mfma_f32_32x32x16_bf16(abl[0], bh0, Cb0, 0, 0, 0);
        Cw1 = __builtin_amdgcn_mfma_f32_32x32x16_bf16(awl[1], bh1, Cw1, 0, 0, 0);
        Cb1 = __builtin_amdgcn_mfma_f32_32x32x16_bf16(abl[1], bh1, Cb1, 0, 0, 0);
    }
    __builtin_amdgcn_s_setprio(0);
    WAVE_SYNC();   // placement fence: next path's stage stores ordered after these reads
}

// ---- R20: two same-shape paths share ONE code body (rolled 2-trip loop) ----
template<int G, int D1>
__device__ __forceinline__ void run_pair(
    int P0, int Z0, int P1, int Z1,
    int el4, int u0, int bvaddr, int avaddr,
    const float (&xr0)[16], const float (&xr1)[16],
    const unsigned short* __restrict__ Awhi, const unsigned short* __restrict__ Awlo,
    const unsigned short* __restrict__ Abhi, const unsigned short* __restrict__ Ablo,
    const float* sz,
    unsigned short* sbh, unsigned short* sbl,
    f32x16 &Cw0, f32x16 &Cb0, f32x16 &Cw1, f32x16 &Cb1)
{
#pragma unroll 1
    for (int r = 0; r < 2; ++r) {
        path_body<G, D1>(r ? P1 : P0, r ? Z1 : Z0,
                         el4, u0, bvaddr, avaddr, xr0, xr1,
                         Awhi, Awlo, Abhi, Ablo, sz, sbh, sbl, Cw0, Cb0, Cw1, Cb1);
    }
}

// ---- one l3 group: batched z, then deduped per-path tmp+MFMA; epilogue into s_msg ----
template<int G>
__device__ __forceinline__ void do_group(
    int lane, int el4, int u0, int bvaddr, int avaddr,
    const float (&xr0)[16], const float (&xr1)[16],
    const float* __restrict__ w3j,
    const unsigned short* __restrict__ Awhi, const unsigned short* __restrict__ Awlo,
    const unsigned short* __restrict__ Abhi, const unsigned short* __restrict__ Ablo,
    const float* sY, float* sz,
    unsigned short* sbh, unsigned short* sbl,
    const float* slen, float* smsg)
{
    constexpr int d3 = 2*G+1;
    constexpr int n = grpN(G);
    f32x16 Cw0 = (f32x16)(0.f), Cb0 = (f32x16)(0.f);
    f32x16 Cw1 = (f32x16)(0.f), Cb1 = (f32x16)(0.f);

    // batched z: all paths of the group (z writes ordered before z reads by in-order DS)
    do_zpath<G, pSlot(G,0), zO(G,0)>(lane, w3j, sY, sz);
    do_zpath<G, pSlot(G,1), zO(G,1)>(lane, w3j, sY, sz);
    do_zpath<G, pSlot(G,2), zO(G,2)>(lane, w3j, sY, sz);
    do_zpath<G, pSlot(G,3), zO(G,3)>(lane, w3j, sY, sz);
    if constexpr (n > 4) do_zpath<G, pSlot(G,4), zO(G,4)>(lane, w3j, sY, sz);
    if constexpr (n > 5) do_zpath<G, pSlot(G,5), zO(G,5)>(lane, w3j, sY, sz);
    if constexpr (n > 6) do_zpath<G, pSlot(G,6), zO(G,6)>(lane, w3j, sY, sz);
    WAVE_SYNC();

    // path phase, same path ORDER as R11 (slots ascending).
    if constexpr (G == 0) {
        path_body<0,1>(pOffA(0,0), zOff4(0,0), el4,u0,bvaddr,avaddr,xr0,xr1,Awhi,Awlo,Abhi,Ablo,sz,sbh,sbl,Cw0,Cb0,Cw1,Cb1);
        path_body<0,3>(pOffA(0,1), zOff4(0,1), el4,u0,bvaddr,avaddr,xr0,xr1,Awhi,Awlo,Abhi,Ablo,sz,sbh,sbl,Cw0,Cb0,Cw1,Cb1);
        path_body<0,5>(pOffA(0,2), zOff4(0,2), el4,u0,bvaddr,avaddr,xr0,xr1,Awhi,Awlo,Abhi,Ablo,sz,sbh,sbl,Cw0,Cb0,Cw1,Cb1);
        path_body<0,7>(pOffA(0,3), zOff4(0,3), el4,u0,bvaddr,avaddr,xr0,xr1,Awhi,Awlo,Abhi,Ablo,sz,sbh,sbl,Cw0,Cb0,Cw1,Cb1);
    } else if constexpr (G == 1) {
        path_body<1,1>(pOffA(1,0), zOff4(1,0), el4,u0,bvaddr,avaddr,xr0,xr1,Awhi,Awlo,Abhi,Ablo,sz,sbh,sbl,Cw0,Cb0,Cw1,Cb1);
        run_pair <1,3>(pOffA(1,1), zOff4(1,1), pOffA(1,2), zOff4(1,2), el4,u0,bvaddr,avaddr,xr0,xr1,Awhi,Awlo,Abhi,Ablo,sz,sbh,sbl,Cw0,Cb0,Cw1,Cb1);
        run_pair <1,5>(pOffA(1,3), zOff4(1,3), pOffA(1,4), zOff4(1,4), el4,u0,bvaddr,avaddr,xr0,xr1,Awhi,Awlo,Abhi,Ablo,sz,sbh,sbl,Cw0,Cb0,Cw1,Cb1);
        path_body<1,7>(pOffA(1,5), zOff4(1,5), el4,u0,bvaddr,avaddr,xr0,xr1,Awhi,Awlo,Abhi,Ablo,sz,sbh,sbl,Cw0,Cb0,Cw1,Cb1);
    } else if constexpr (G == 2) {
        path_body<2,1>(pOffA(2,0), zOff4(2,0), el4,u0,bvaddr,avaddr,xr0,xr1,Awhi,Awlo,Abhi,Ablo,sz,sbh,sbl,Cw0,Cb0,Cw1,Cb1);
        run_pair <2,3>(pOffA(2,1), zOff4(2,1), pOffA(2,2), zOff4(2,2), el4,u0,bvaddr,avaddr,xr0,xr1,Awhi,Awlo,Abhi,Ablo,sz,sbh,sbl,Cw0,Cb0,Cw1,Cb1);
        run_pair <2,5>(pOffA(2,3), zOff4(2,3), pOffA(2,4), zOff4(2,4), el4,u0,bvaddr,avaddr,xr0,xr1,Awhi,Awlo,Abhi,Ablo,sz,sbh,sbl,Cw0,Cb0,Cw1,Cb1);
        run_pair <2,7>(pOffA(2,5), zOff4(2,5), pOffA(2,6), zOff4(2,6), el4,u0,bvaddr,avaddr,xr0,xr1,Awhi,Awlo,Abhi,Ablo,sz,sbh,sbl,Cw0,Cb0,Cw1,Cb1);
    } else {
        path_body<3,1>(pOffA(3,0), zOff4(3,0), el4,u0,bvaddr,avaddr,xr0,xr1,Awhi,Awlo,Abhi,Ablo,sz,sbh,sbl,Cw0,Cb0,Cw1,Cb1);
        path_body<3,3>(pOffA(3,1), zOff4(3,1), el4,u0,bvaddr,avaddr,xr0,xr1,Awhi,Awlo,Abhi,Ablo,sz,sbh,sbl,Cw0,Cb0,Cw1,Cb1);
        run_pair <3,5>(pOffA(3,2), zOff4(3,2), pOffA(3,3), zOff4(3,3), el4,u0,bvaddr,avaddr,xr0,xr1,Awhi,Awlo,Abhi,Ablo,sz,sbh,sbl,Cw0,Cb0,Cw1,Cb1);
        run_pair <3,7>(pOffA(3,4), zOff4(3,4), pOffA(3,5), zOff4(3,5), el4,u0,bvaddr,avaddr,xr0,xr1,Awhi,Awlo,Abhi,Ablo,sz,sbh,sbl,Cw0,Cb0,Cw1,Cb1);
    }

    // epilogue: msg = len*(Cw0+Cw1) + (Cb0+Cb1)
    // C/D layout (verified m74/m101): col=lane&31, row=(reg&3)+8*(reg>>2)+4*(lane>>5)
    const int col = lane & 31;
    if (col < 4*d3) {
        const int elc = col / d3, k = col - elc*d3;   // const-div
        const float len = slen[elc];
        float* mp = smsg + elc*FEAT + cOFF3[G] + k;
#pragma unroll
        for (int reg = 0; reg < 16; ++reg) {
            const int w = (reg & 3) + 8*(reg >> 2) + 4*(lane >> 5);
            mp[w*d3] = fmaf(len, Cw0[reg] + Cw1[reg], Cb0[reg] + Cb1[reg]);
        }
    }
}

// ---- main: 2 waves/block, 4 edges/wave (R20 + R22 soft fences + R25 split acc) ----
__global__ __launch_bounds__(BLK) void edge_kernel(
    const float* __restrict__ nf,
    const int*   __restrict__ eidx,
    const float* __restrict__ ev,
    const float* __restrict__ w3j,
    const unsigned short* __restrict__ Awhi,
    const unsigned short* __restrict__ Awlo,
    const unsigned short* __restrict__ Abhi,
    const unsigned short* __restrict__ Ablo,
    float*       __restrict__ out)
{
    __shared__ float s_zp[2][784];       // batched per-group z (max G3: 4*196)
    __shared__ float s_Y[2][64];
    __shared__ float s_len[2][4];
    __shared__ int   s_src[2][4];
    __shared__ int   s_dst[2][4];
    __shared__ __align__(16) unsigned short s_Bhi[2][1280];  // [col(32)][u(32)+pad8]
    __shared__ __align__(16) unsigned short s_Blo[2][1280];
    __shared__ float s_msg[2][4*FEAT];

    const int t    = threadIdx.x;
    const int wave = t >> 6;
    const int lane = t & 63;
    const int el4  = lane >> 4;      // tmp-phase edge (4 per wave)
    const int u0   = lane & 15;      // tmp-phase u-pair index
    const int e0   = blockIdx.x * 8 + wave*4;
    const int bvaddr = (lane & 31)*40 + (lane >> 5)*8;   // B: n=lane&31, k0=(lane>>5)*8
    const int avaddr = (lane & 31)*32 + (lane >> 5)*8;   // A: m=lane&31, k0=(lane>>5)*8

    if (lane < 4) {
        const int e = e0 + lane;
        s_src[wave][lane] = eidx[e];
        s_dst[wave][lane] = eidx[N_EDGES + e];
        const float x = ev[e*3+0], y = ev[e*3+1], z = ev[e*3+2];
        const float len = sqrtf(x*x + y*y + z*z);
        const float lc = fmaxf(len, 1e-8f);
        s_len[wave][lane] = lc;
        float Yl[16];
        sh_f32(x/lc, y/lc, z/lc, Yl);
#pragma unroll
        for (int i = 0; i < 16; ++i) s_Y[wave][lane*16+i] = Yl[i];
    }
    WAVE_SYNC();

    // preload this lane's 2 u-rows of x (u = 2u0, 2u0+1) into registers
    float xr0[16], xr1[16];
    {
        const float* xrow = nf + (size_t)s_src[wave][el4]*FEAT;
        const int ua = 2*u0, ub = 2*u0 + 1;
        xr0[0] = xrow[ua];                 xr1[0] = xrow[ub];
#pragma unroll
        for (int i = 0; i < 3; ++i) { xr0[1+i] = xrow[32 + ua*3 + i];  xr1[1+i] = xrow[32 + ub*3 + i]; }
#pragma unroll
        for (int i = 0; i < 5; ++i) { xr0[4+i] = xrow[128 + ua*5 + i]; xr1[4+i] = xrow[128 + ub*5 + i]; }
#pragma unroll
        for (int i = 0; i < 7; ++i) { xr0[9+i] = xrow[288 + ua*7 + i]; xr1[9+i] = xrow[288 + ub*7 + i]; }
    }

    do_group<0>(lane,el4,u0,bvaddr,avaddr,xr0,xr1,w3j,Awhi,Awlo,Abhi,Ablo,
                s_Y[wave], s_zp[wave], s_Bhi[wave], s_Blo[wave], s_len[wave], s_msg[wave]);
    do_group<1>(lane,el4,u0,bvaddr,avaddr,xr0,xr1,w3j,Awhi,Awlo,Abhi,Ablo,
                s_Y[wave], s_zp[wave], s_Bhi[wave], s_Blo[wave], s_len[wave], s_msg[wave]);
    do_group<2>(lane,el4,u0,bvaddr,avaddr,xr0,xr1,w3j,Awhi,Awlo,Abhi,Ablo,
                s_Y[wave], s_zp[wave], s_Bhi[wave], s_Blo[wave], s_len[wave], s_msg[wave]);
    do_group<3>(lane,el4,u0,bvaddr,avaddr,xr0,xr1,w3j,Awhi,Awlo,Abhi,Ablo,
                s_Y[wave], s_zp[wave], s_Bhi[wave], s_Blo[wave], s_len[wave], s_msg[wave]);
    WAVE_SYNC();

    // wave-local coalesced scatter: 4 edges x 512 (R11 actor pattern)
    for (int i = lane; i < 4*FEAT; i += 64) {
        const int elc = i >> 9, m = i & 511;
        atomicAdd(&out[(size_t)s_dst[wave][elc]*FEAT + m], s_msg[wave][i]);
    }
}

extern "C" void kernel_launch(void* const* d_in, const int* in_sizes, int n_in,
                              void* d_out, int out_size, void* d_ws, size_t ws_size,
                              hipStream_t stream) {
    const float* nf   = (const float*)d_in[0];
    const int*   eidx = (const int*)  d_in[1];
    const float* ev   = (const float*)d_in[2];
    const float* ww   = (const float*)d_in[3];
    const float* wb   = (const float*)d_in[4];
    float* out = (float*)d_out;

    float* w3j = (float*)d_ws;                                   // 7500 B
    unsigned short* Awhi = (unsigned short*)((char*)d_ws + 16384);
    unsigned short* Awlo = Awhi + N_PATHS*1024;
    unsigned short* Abhi = Awlo + N_PATHS*1024;
    unsigned short* Ablo = Abhi + N_PATHS*1024;                  // ends at 204800 B

    w3j_setup_kernel<<<N_PATHS + ZERO_BLOCKS, 512, 0, stream>>>(
        ww, wb, w3j, Awhi, Awlo, Abhi, Ablo, out);
    edge_kernel<<<N_EDGES/8, BLK, 0, stream>>>(nf, eidx, ev, w3j, Awhi, Awlo, Abhi, Ablo, out);
}